// Round 8
// baseline (251.031 us; speedup 1.0000x reference)
//
#include <hip/hip_runtime.h>
#include <hip/hip_bf16.h>
#include <cstdint>
#include <cstddef>

// Problem constants (from reference)
constexpr int NN   = 50000;          // nodes
constexpr int EE   = 800000;         // edges (before self-loops)
constexpr int ETOT = EE + NN;        // edges + self loops
constexpr int HC   = 128;            // heads * per-head channels
constexpr float SLOPE = 0.2f;        // leaky_relu slope
constexpr int CAP  = 64;             // slot capacity (Poisson(17): P(>64)~1e-17)
constexpr int CSTR = 16;             // cnt stride (1 counter per 64B line)
constexpr int EBLOCKS = (ETOT + 255) / 256;   // 3321
constexpr int GB      = (NN + 63) / 64;       // 782 gemm blocks

typedef float f32x4  __attribute__((ext_vector_type(4)));
typedef short bf16x8 __attribute__((ext_vector_type(8)));

// Column permutation: orig col c -> storage position p = (c&15)*8 + (c>>4).
// orig(p) = (p>>3) + ((p&7)<<4).  Chosen so the MFMA D-fragment
// (col = lane&15, row = (lane>>4)*4 + reg) writes one contiguous uint4 per
// row per lane.  W2's k-rows, att vectors and biases are permuted to match;
// only the final root-gather writes orig layout.

__device__ __forceinline__ ushort f2b(float f) {
  union { __hip_bfloat16 h; ushort u; } c;
  c.h = __float2bfloat16(f);
  return c.u;
}
__device__ __forceinline__ float b2f_lo(uint u) { return __uint_as_float(u << 16); }
__device__ __forceinline__ float b2f_hi(uint u) { return __uint_as_float(u & 0xffff0000u); }

union frag_cvt { uint4 u; bf16x8 b; };

// ---------------------------------------------------------------------------
// Prep: pack W1/W2 into MFMA B-fragment order (bf16), permute small vectors,
// and zero the (strided) slot counters.  Grid: 224 x 256 = 57344 threads.
// ---------------------------------------------------------------------------
__global__ __launch_bounds__(256)
void prep(const float* __restrict__ W1, const float* __restrict__ W2,
          const float* __restrict__ as1, const float* __restrict__ ad1,
          const float* __restrict__ b1,  const float* __restrict__ as2,
          const float* __restrict__ ad2, const float* __restrict__ b2,
          ushort* __restrict__ W1t, ushort* __restrict__ W2t,
          float* __restrict__ vecs, int* __restrict__ cnt) {
  const int tid = blockIdx.x * 256 + threadIdx.x;
  if (tid < NN) cnt[tid * CSTR] = 0;
  if (tid < 4096) {                       // W1: 8 chunks x 8 coltiles x 64
    const int m = tid & 63, c = (tid >> 6) & 7, q = tid >> 9;
    const int kb = q * 32 + (m >> 4) * 8, n = c * 16 + (m & 15);
    #pragma unroll
    for (int j = 0; j < 8; ++j)
      W1t[tid * 8 + j] = f2b(W1[(size_t)(kb + j) * HC + n]);
  } else if (tid < 4096 + 2048) {         // W2: 4 chunks x 8 coltiles x 64
    const int t = tid - 4096;
    const int m = t & 63, c = (t >> 6) & 7, q = t >> 9;
    const int n = c * 16 + (m & 15);
    #pragma unroll
    for (int j = 0; j < 8; ++j) {
      const int p  = q * 32 + (m >> 4) * 8 + j;
      const int ko = (p >> 3) + ((p & 7) << 4);
      W2t[t * 8 + j] = f2b(W2[(size_t)ko * HC + n]);
    }
  } else if (tid < 4096 + 2048 + 768) {   // 6 vectors of 128, perm order
    const int t = tid - 4096 - 2048;
    const int p = t & 127, which = t >> 7;
    const int c = (p >> 3) + ((p & 7) << 4);
    const float* src = which == 0 ? as1 : which == 1 ? ad1 : which == 2 ? b1
                     : which == 3 ? as2 : which == 4 ? ad2 : b2;
    vecs[which * 128 + p] = src[c];
  }
}

// ---------------------------------------------------------------------------
// MFMA GEMM body + attention coefficients. 256 threads = 4 waves; each wave
// owns a 16-row band x all 128 cols (8 col-tiles), K in chunks of 32. No LDS.
// ---------------------------------------------------------------------------
template <int K>
__device__ __forceinline__
void gemm_body(int bid, const float* __restrict__ Xf,
               const ushort* __restrict__ Xb, const ushort* __restrict__ Wt,
               const float* __restrict__ attsp, const float* __restrict__ attdp,
               ushort* __restrict__ XPp, float* __restrict__ AS,
               float* __restrict__ AD) {
  const int l   = threadIdx.x & 63;
  const int wid = threadIdx.x >> 6;
  const int m0  = (bid * 4 + wid) * 16;
  const int lr  = l & 15, lg = l >> 4;
  const int arow = m0 + lr;
  const bool rowok = arow < NN;

  f32x4 acc[8];
  #pragma unroll
  for (int t = 0; t < 8; ++t) acc[t] = (f32x4)0.0f;

  for (int q = 0; q < K / 32; ++q) {
    frag_cvt a;
    if constexpr (K == 256) {
      float4 v0 = make_float4(0.f, 0.f, 0.f, 0.f), v1 = v0;
      if (rowok) {
        const float* p = Xf + (size_t)arow * K + q * 32 + lg * 8;
        v0 = *(const float4*)p;
        v1 = *(const float4*)(p + 4);
      }
      a.u.x = (uint)f2b(v0.x) | ((uint)f2b(v0.y) << 16);
      a.u.y = (uint)f2b(v0.z) | ((uint)f2b(v0.w) << 16);
      a.u.z = (uint)f2b(v1.x) | ((uint)f2b(v1.y) << 16);
      a.u.w = (uint)f2b(v1.z) | ((uint)f2b(v1.w) << 16);
    } else {
      a.u = rowok ? *(const uint4*)(Xb + (size_t)arow * K + q * 32 + lg * 8)
                  : make_uint4(0, 0, 0, 0);
    }
    const uint4* wq = (const uint4*)Wt + (size_t)(q * 8) * 64 + l;
    #pragma unroll
    for (int t = 0; t < 8; ++t) {
      frag_cvt b;
      b.u = wq[t * 64];
      acc[t] = __builtin_amdgcn_mfma_f32_16x16x32_bf16(a.b, b.b, acc[t],
                                                       0, 0, 0);
    }
  }

  // ---- epilogue ----
  float4 ap0 = *(const float4*)(attsp + lr * 8);
  float4 ap1 = *(const float4*)(attsp + lr * 8 + 4);
  float4 dp0 = *(const float4*)(attdp + lr * 8);
  float4 dp1 = *(const float4*)(attdp + lr * 8 + 4);
  const float av[8] = {ap0.x, ap0.y, ap0.z, ap0.w, ap1.x, ap1.y, ap1.z, ap1.w};
  const float dv[8] = {dp0.x, dp0.y, dp0.z, dp0.w, dp1.x, dp1.y, dp1.z, dp1.w};

  #pragma unroll
  for (int r = 0; r < 4; ++r) {
    const int orow = m0 + lg * 4 + r;
    const bool ok = orow < NN;
    if (ok) {
      uint4 pk;
      pk.x = (uint)f2b(acc[0][r]) | ((uint)f2b(acc[1][r]) << 16);
      pk.y = (uint)f2b(acc[2][r]) | ((uint)f2b(acc[3][r]) << 16);
      pk.z = (uint)f2b(acc[4][r]) | ((uint)f2b(acc[5][r]) << 16);
      pk.w = (uint)f2b(acc[6][r]) | ((uint)f2b(acc[7][r]) << 16);
      *(uint4*)(XPp + (size_t)orow * HC + lr * 8) = pk;
    }
    float s0 = acc[0][r] * av[0] + acc[1][r] * av[1];
    float s1 = acc[2][r] * av[2] + acc[3][r] * av[3];
    float s2 = acc[4][r] * av[4] + acc[5][r] * av[5];
    float s3 = acc[6][r] * av[6] + acc[7][r] * av[7];
    float d0 = acc[0][r] * dv[0] + acc[1][r] * dv[1];
    float d1 = acc[2][r] * dv[2] + acc[3][r] * dv[3];
    float d2 = acc[4][r] * dv[4] + acc[5][r] * dv[5];
    float d3 = acc[6][r] * dv[6] + acc[7][r] * dv[7];
    #pragma unroll
    for (int o = 1; o < 16; o <<= 1) {
      s0 += __shfl_xor(s0, o); s1 += __shfl_xor(s1, o);
      s2 += __shfl_xor(s2, o); s3 += __shfl_xor(s3, o);
      d0 += __shfl_xor(d0, o); d1 += __shfl_xor(d1, o);
      d2 += __shfl_xor(d2, o); d3 += __shfl_xor(d3, o);
    }
    if (lr == 0 && ok) {
      *(float4*)(AS + (size_t)orow * 4) = make_float4(s0, s1, s2, s3);
      *(float4*)(AD + (size_t)orow * 4) = make_float4(d0, d1, d2, d3);
    }
  }
}

// ---------------------------------------------------------------------------
// Fused: slot-CSR fill (blocks [0,EBLOCKS)) || layer-1 GEMM (rest).
// The two parts are independent; fill is latency/atomic-bound with ~0% VALU,
// gemm is MFMA/memory-bound -> overlap. cnt strided so each counter owns a
// 64-B line (kills same-line atomic serialization).
// ---------------------------------------------------------------------------
__device__ __forceinline__ void edge_sd(const int* __restrict__ ei, int e,
                                        int& s, int& d) {
  if (e < EE) { s = ei[e]; d = ei[EE + e]; }
  else        { s = e - EE; d = s; }
}

__global__ __launch_bounds__(256)
void fill_gemm1(const int* __restrict__ ei, int* __restrict__ cnt,
                int* __restrict__ slots, const float* __restrict__ Xf,
                const ushort* __restrict__ Wt,
                const float* __restrict__ attsp, const float* __restrict__ attdp,
                ushort* __restrict__ XPp, float* __restrict__ AS,
                float* __restrict__ AD) {
  if (blockIdx.x < EBLOCKS) {
    int e = blockIdx.x * 256 + threadIdx.x;
    if (e >= ETOT) return;
    int s, d; edge_sd(ei, e, s, d);
    int pos = atomicAdd(cnt + d * CSTR, 1);
    if (pos < CAP) slots[((size_t)d << 6) + pos] = s;
  } else {
    gemm_body<256>(blockIdx.x - EBLOCKS, Xf, nullptr, Wt, attsp, attdp,
                   XPp, AS, AD);
  }
}

__global__ __launch_bounds__(256)
void gemm2(const ushort* __restrict__ Xb, const ushort* __restrict__ Wt,
           const float* __restrict__ attsp, const float* __restrict__ attdp,
           ushort* __restrict__ XPp, float* __restrict__ AS,
           float* __restrict__ AD) {
  gemm_body<128>(blockIdx.x, nullptr, Xb, Wt, attsp, attdp, XPp, AS, AD);
}

// ---------------------------------------------------------------------------
// Aggregate: 4 nodes per 256-thread block, one 64-lane wave per node.
// No LDS, no barriers. Slot row preloaded into one register/lane (single
// coalesced load), broadcast via __shfl in the loop; 4-edge unroll -> 8
// outstanding random loads per wave. Max-free softmax (logits O(1)).
// ---------------------------------------------------------------------------
__device__ __forceinline__ float wcalc(const float* AS, int s, int h, float adh) {
  float x = AS[(size_t)s * 4 + h] + adh;
  x = fmaxf(x, SLOPE * x);
  return __expf(x);
}

template <bool ROOT>
__global__ __launch_bounds__(256)
void aggregate(const int* __restrict__ roots, const int* __restrict__ cnt,
               const int* __restrict__ slots,
               const float* __restrict__ AS, const float* __restrict__ AD,
               const uint* __restrict__ XPu, const float* __restrict__ bvp,
               void* __restrict__ outp) {
  const int nid = blockIdx.x * 4 + (threadIdx.x >> 6);
  const int node = ROOT ? roots[nid] : nid;
  const int l = threadIdx.x & 63;
  const int h = l & 3;
  const int deg = min(cnt[node * CSTR], CAP);
  const size_t base = (size_t)node << 6;
  const float adh = AD[((size_t)node << 2) + h];
  const int si = slots[base + l];         // own slot entry (garbage if l>=deg)

  float ax = 0.f, ay = 0.f, den = 0.f;
  int e = 0;
  for (; e + 4 <= deg; e += 4) {
    const int s0 = __shfl(si, e),     s1 = __shfl(si, e + 1);
    const int s2 = __shfl(si, e + 2), s3 = __shfl(si, e + 3);
    const uint u0 = XPu[((size_t)s0 << 6) + l];
    const uint u1 = XPu[((size_t)s1 << 6) + l];
    const uint u2 = XPu[((size_t)s2 << 6) + l];
    const uint u3 = XPu[((size_t)s3 << 6) + l];
    const float w0 = wcalc(AS, s0, h, adh), w1 = wcalc(AS, s1, h, adh);
    const float w2 = wcalc(AS, s2, h, adh), w3 = wcalc(AS, s3, h, adh);
    ax += w0 * b2f_lo(u0) + w1 * b2f_lo(u1) + w2 * b2f_lo(u2) + w3 * b2f_lo(u3);
    ay += w0 * b2f_hi(u0) + w1 * b2f_hi(u1) + w2 * b2f_hi(u2) + w3 * b2f_hi(u3);
    den += (w0 + w1) + (w2 + w3);
  }
  for (; e < deg; ++e) {
    const int s = __shfl(si, e);
    const uint u = XPu[((size_t)s << 6) + l];
    const float w = wcalc(AS, s, h, adh);
    ax += w * b2f_lo(u);
    ay += w * b2f_hi(u);
    den += w;
  }

  const float inv = 1.f / (den + 1e-16f);
  const float2 bv = *(const float2*)(bvp + 2 * l);
  float rx = ax * inv + bv.x;
  float ry = ay * inv + bv.y;
  if (ROOT) {
    const int col0 = 32 * (l & 3) + (l >> 2);   // orig(2l); orig(2l+1)=col0+16
    float* o = (float*)outp + (size_t)nid * HC;
    o[col0] = rx;
    o[col0 + 16] = ry;
  } else {
    rx = fmaxf(rx, 0.f);
    ry = fmaxf(ry, 0.f);
    ((uint*)outp)[((size_t)node << 6) + l] = (uint)f2b(rx) | ((uint)f2b(ry) << 16);
  }
}

// ---------------------------------------------------------------------------
extern "C" void kernel_launch(void* const* d_in, const int* in_sizes, int n_in,
                              void* d_out, int out_size, void* d_ws, size_t ws_size,
                              hipStream_t stream) {
  const float* x    = (const float*)d_in[0];
  const int*   ei   = (const int*)d_in[1];
  const int*   root = (const int*)d_in[2];
  const float* W1   = (const float*)d_in[3];
  const float* as1  = (const float*)d_in[4];
  const float* ad1  = (const float*)d_in[5];
  const float* b1   = (const float*)d_in[6];
  const float* W2   = (const float*)d_in[7];
  const float* as2  = (const float*)d_in[8];
  const float* ad2  = (const float*)d_in[9];
  const float* b2   = (const float*)d_in[10];
  float* out = (float*)d_out;

  // workspace layout (16B-aligned segments), ~43 MB total
  ushort* W1t  = (ushort*)d_ws;                          // 64 KB
  ushort* W2t  = W1t + 4096 * 8;                         // 32 KB
  float*  vecs = (float*)(W2t + 2048 * 8);               // 3 KB
  ushort* XPp  = (ushort*)(vecs + 768);                  // [NN*HC] bf16
  ushort* Hbp  = XPp + (size_t)NN * HC;                  // [NN*HC] bf16
  float*  AS   = (float*)(Hbp + (size_t)NN * HC);        // [NN*4]
  float*  AD   = AS + (size_t)NN * 4;                    // [NN*4]
  int*    cnt  = (int*)(AD + (size_t)NN * 4);            // [NN*CSTR] strided
  int*    slots = cnt + (size_t)NN * CSTR;               // [NN*CAP]

  prep<<<224, 256, 0, stream>>>(W1, W2, as1, ad1, b1, as2, ad2, b2,
                                W1t, W2t, vecs, cnt);

  // ---- layer 1: CSR fill || gemm1 (independent, fused) ----
  fill_gemm1<<<EBLOCKS + GB, 256, 0, stream>>>(ei, cnt, slots, x, W1t,
                                               vecs, vecs + 128,
                                               XPp, AS, AD);
  aggregate<false><<<NN / 4, 256, 0, stream>>>(nullptr, cnt, slots, AS, AD,
                                               (const uint*)XPp, vecs + 256,
                                               Hbp);

  // ---- layer 2 (aggregate only at the 1024 root nodes) ----
  gemm2<<<GB, 256, 0, stream>>>(Hbp, W2t, vecs + 384, vecs + 512,
                                XPp, AS, AD);
  aggregate<true><<<out_size / HC / 4, 256, 0, stream>>>(root, cnt, slots,
                                                         AS, AD,
                                                         (const uint*)XPp,
                                                         vecs + 640, out);
}

// Round 9
// 187.963 us; speedup vs baseline: 1.3355x; 1.3355x over previous
//
#include <hip/hip_runtime.h>
#include <hip/hip_bf16.h>
#include <cstdint>
#include <cstddef>

// Problem constants (from reference)
constexpr int NN   = 50000;          // nodes
constexpr int EE   = 800000;         // edges (before self-loops)
constexpr int ETOT = EE + NN;        // edges + self loops
constexpr int HC   = 128;            // heads * per-head channels
constexpr float SLOPE = 0.2f;        // leaky_relu slope
constexpr int CAP  = 64;             // slot capacity (Poisson(17): P(>64)~1e-20)
constexpr int CSTR = 16;             // cnt stride (1 counter per 64B line)
constexpr int EBLOCKS = (ETOT + 255) / 256;   // 3321
constexpr int GB      = (NN + 63) / 64;       // 782 gemm blocks

typedef float f32x4  __attribute__((ext_vector_type(4)));
typedef short bf16x8 __attribute__((ext_vector_type(8)));

// Column permutation: orig col c -> storage position p = (c&15)*8 + (c>>4).
// orig(p) = (p>>3) + ((p&7)<<4).  Chosen so the MFMA D-fragment
// (col = lane&15, row = (lane>>4)*4 + reg) writes one contiguous uint4 per
// row per lane.  W2's k-rows, att vectors and biases are permuted to match;
// only the final root-gather writes orig layout.
//
// Two-hop pruning: output = 1024 root rows only.  N1 = roots U in(roots)
// (~18k nodes).  Slot lists + layer-1 aggregation + layer-2 usage only at
// N1; gemm1 stays full (N1's in-neighbors span ~all nodes).

__device__ __forceinline__ ushort f2b(float f) {
  union { __hip_bfloat16 h; ushort u; } c;
  c.h = __float2bfloat16(f);
  return c.u;
}
__device__ __forceinline__ float b2f_lo(uint u) { return __uint_as_float(u << 16); }
__device__ __forceinline__ float b2f_hi(uint u) { return __uint_as_float(u & 0xffff0000u); }

union frag_cvt { uint4 u; bf16x8 b; };

// ---------------------------------------------------------------------------
// Prep: pack W1/W2 into MFMA B-fragment order (bf16), permute small vectors,
// zero cnt/need/rflag.  Grid: 224 x 256 = 57344 threads.
// ---------------------------------------------------------------------------
__global__ __launch_bounds__(256)
void prep(const float* __restrict__ W1, const float* __restrict__ W2,
          const float* __restrict__ as1, const float* __restrict__ ad1,
          const float* __restrict__ b1,  const float* __restrict__ as2,
          const float* __restrict__ ad2, const float* __restrict__ b2,
          ushort* __restrict__ W1t, ushort* __restrict__ W2t,
          float* __restrict__ vecs, int* __restrict__ cnt,
          char* __restrict__ need, char* __restrict__ rflag) {
  const int tid = blockIdx.x * 256 + threadIdx.x;
  if (tid < NN) {
    cnt[tid * CSTR] = 0;
    need[tid] = 0;
    rflag[tid] = 0;
  }
  if (tid < 4096) {                       // W1: 8 chunks x 8 coltiles x 64
    const int m = tid & 63, c = (tid >> 6) & 7, q = tid >> 9;
    const int kb = q * 32 + (m >> 4) * 8, n = c * 16 + (m & 15);
    #pragma unroll
    for (int j = 0; j < 8; ++j)
      W1t[tid * 8 + j] = f2b(W1[(size_t)(kb + j) * HC + n]);
  } else if (tid < 4096 + 2048) {         // W2: 4 chunks x 8 coltiles x 64
    const int t = tid - 4096;
    const int m = t & 63, c = (t >> 6) & 7, q = t >> 9;
    const int n = c * 16 + (m & 15);
    #pragma unroll
    for (int j = 0; j < 8; ++j) {
      const int p  = q * 32 + (m >> 4) * 8 + j;
      const int ko = (p >> 3) + ((p & 7) << 4);
      W2t[t * 8 + j] = f2b(W2[(size_t)ko * HC + n]);
    }
  } else if (tid < 4096 + 2048 + 768) {   // 6 vectors of 128, perm order
    const int t = tid - 4096 - 2048;
    const int p = t & 127, which = t >> 7;
    const int c = (p >> 3) + ((p & 7) << 4);
    const float* src = which == 0 ? as1 : which == 1 ? ad1 : which == 2 ? b1
                     : which == 3 ? as2 : which == 4 ? ad2 : b2;
    vecs[which * 128 + p] = src[c];
  }
}

__global__ __launch_bounds__(256)
void mark_roots(const int* __restrict__ root, char* __restrict__ need,
                char* __restrict__ rflag, int n_root) {
  const int i = blockIdx.x * 256 + threadIdx.x;
  if (i < n_root) {
    const int r = root[i];
    rflag[r] = 1;
    need[r] = 1;
  }
}

// ---------------------------------------------------------------------------
// pass1: mark in-neighbors of roots (need[s]=1 where dst is a root).
// Benign byte-store races (all writers store 1).
// ---------------------------------------------------------------------------
__device__ __forceinline__ void edge_sd(const int* __restrict__ ei, int e,
                                        int& s, int& d) {
  if (e < EE) { s = ei[e]; d = ei[EE + e]; }
  else        { s = e - EE; d = s; }
}

__global__ __launch_bounds__(256)
void pass1(const int* __restrict__ ei, const char* __restrict__ rflag,
           char* __restrict__ need) {
  int e = blockIdx.x * 256 + threadIdx.x;
  if (e >= ETOT) return;
  int s, d; edge_sd(ei, e, s, d);
  if (rflag[d]) need[s] = 1;
}

// ---------------------------------------------------------------------------
// fill: slot lists (ushort src) only for needed destinations (~37% of edges).
// ---------------------------------------------------------------------------
__global__ __launch_bounds__(256)
void fillk(const int* __restrict__ ei, const char* __restrict__ need,
           int* __restrict__ cnt, ushort* __restrict__ slots) {
  int e = blockIdx.x * 256 + threadIdx.x;
  if (e >= ETOT) return;
  int s, d; edge_sd(ei, e, s, d);
  if (need[d]) {
    int pos = atomicAdd(cnt + d * CSTR, 1);
    if (pos < CAP) slots[((size_t)d << 6) + pos] = (ushort)s;
  }
}

// ---------------------------------------------------------------------------
// MFMA GEMM + attention coefficients. 256 threads = 4 waves; each wave owns
// a 16-row band x all 128 cols (8 col-tiles), K in chunks of 32. No LDS.
// ---------------------------------------------------------------------------
template <int K>
__device__ __forceinline__
void gemm_body(int bid, const float* __restrict__ Xf,
               const ushort* __restrict__ Xb, const ushort* __restrict__ Wt,
               const float* __restrict__ attsp, const float* __restrict__ attdp,
               ushort* __restrict__ XPp, float* __restrict__ AS,
               float* __restrict__ AD) {
  const int l   = threadIdx.x & 63;
  const int wid = threadIdx.x >> 6;
  const int m0  = (bid * 4 + wid) * 16;
  const int lr  = l & 15, lg = l >> 4;
  const int arow = m0 + lr;
  const bool rowok = arow < NN;

  f32x4 acc[8];
  #pragma unroll
  for (int t = 0; t < 8; ++t) acc[t] = (f32x4)0.0f;

  for (int q = 0; q < K / 32; ++q) {
    frag_cvt a;
    if constexpr (K == 256) {
      float4 v0 = make_float4(0.f, 0.f, 0.f, 0.f), v1 = v0;
      if (rowok) {
        const float* p = Xf + (size_t)arow * K + q * 32 + lg * 8;
        v0 = *(const float4*)p;
        v1 = *(const float4*)(p + 4);
      }
      a.u.x = (uint)f2b(v0.x) | ((uint)f2b(v0.y) << 16);
      a.u.y = (uint)f2b(v0.z) | ((uint)f2b(v0.w) << 16);
      a.u.z = (uint)f2b(v1.x) | ((uint)f2b(v1.y) << 16);
      a.u.w = (uint)f2b(v1.z) | ((uint)f2b(v1.w) << 16);
    } else {
      a.u = rowok ? *(const uint4*)(Xb + (size_t)arow * K + q * 32 + lg * 8)
                  : make_uint4(0, 0, 0, 0);
    }
    const uint4* wq = (const uint4*)Wt + (size_t)(q * 8) * 64 + l;
    #pragma unroll
    for (int t = 0; t < 8; ++t) {
      frag_cvt b;
      b.u = wq[t * 64];
      acc[t] = __builtin_amdgcn_mfma_f32_16x16x32_bf16(a.b, b.b, acc[t],
                                                       0, 0, 0);
    }
  }

  // ---- epilogue ----
  float4 ap0 = *(const float4*)(attsp + lr * 8);
  float4 ap1 = *(const float4*)(attsp + lr * 8 + 4);
  float4 dp0 = *(const float4*)(attdp + lr * 8);
  float4 dp1 = *(const float4*)(attdp + lr * 8 + 4);
  const float av[8] = {ap0.x, ap0.y, ap0.z, ap0.w, ap1.x, ap1.y, ap1.z, ap1.w};
  const float dv[8] = {dp0.x, dp0.y, dp0.z, dp0.w, dp1.x, dp1.y, dp1.z, dp1.w};

  #pragma unroll
  for (int r = 0; r < 4; ++r) {
    const int orow = m0 + lg * 4 + r;
    const bool ok = orow < NN;
    if (ok) {
      uint4 pk;
      pk.x = (uint)f2b(acc[0][r]) | ((uint)f2b(acc[1][r]) << 16);
      pk.y = (uint)f2b(acc[2][r]) | ((uint)f2b(acc[3][r]) << 16);
      pk.z = (uint)f2b(acc[4][r]) | ((uint)f2b(acc[5][r]) << 16);
      pk.w = (uint)f2b(acc[6][r]) | ((uint)f2b(acc[7][r]) << 16);
      *(uint4*)(XPp + (size_t)orow * HC + lr * 8) = pk;
    }
    float s0 = acc[0][r] * av[0] + acc[1][r] * av[1];
    float s1 = acc[2][r] * av[2] + acc[3][r] * av[3];
    float s2 = acc[4][r] * av[4] + acc[5][r] * av[5];
    float s3 = acc[6][r] * av[6] + acc[7][r] * av[7];
    float d0 = acc[0][r] * dv[0] + acc[1][r] * dv[1];
    float d1 = acc[2][r] * dv[2] + acc[3][r] * dv[3];
    float d2 = acc[4][r] * dv[4] + acc[5][r] * dv[5];
    float d3 = acc[6][r] * dv[6] + acc[7][r] * dv[7];
    #pragma unroll
    for (int o = 1; o < 16; o <<= 1) {
      s0 += __shfl_xor(s0, o); s1 += __shfl_xor(s1, o);
      s2 += __shfl_xor(s2, o); s3 += __shfl_xor(s3, o);
      d0 += __shfl_xor(d0, o); d1 += __shfl_xor(d1, o);
      d2 += __shfl_xor(d2, o); d3 += __shfl_xor(d3, o);
    }
    if (lr == 0 && ok) {
      *(float4*)(AS + (size_t)orow * 4) = make_float4(s0, s1, s2, s3);
      *(float4*)(AD + (size_t)orow * 4) = make_float4(d0, d1, d2, d3);
    }
  }
}

__global__ __launch_bounds__(256)
void gemm1(const float* __restrict__ Xf, const ushort* __restrict__ Wt,
           const float* __restrict__ attsp, const float* __restrict__ attdp,
           ushort* __restrict__ XPp, float* __restrict__ AS,
           float* __restrict__ AD) {
  gemm_body<256>(blockIdx.x, Xf, nullptr, Wt, attsp, attdp, XPp, AS, AD);
}

__global__ __launch_bounds__(256)
void gemm2(const ushort* __restrict__ Xb, const ushort* __restrict__ Wt,
           const float* __restrict__ attsp, const float* __restrict__ attdp,
           ushort* __restrict__ XPp, float* __restrict__ AS,
           float* __restrict__ AD) {
  gemm_body<128>(blockIdx.x, nullptr, Xb, Wt, attsp, attdp, XPp, AS, AD);
}

// ---------------------------------------------------------------------------
// Aggregate: 4 nodes per 256-thread block, one 64-lane wave per node.
// No LDS, no barriers; need-gated wave-uniform early exit (non-ROOT).
// Slot row preloaded (64 x 2B coalesced), __shfl broadcast; 4-edge unroll.
// Max-free softmax (logits O(1) by input scaling).
// ---------------------------------------------------------------------------
__device__ __forceinline__ float wcalc(const float* AS, int s, int h, float adh) {
  float x = AS[(size_t)s * 4 + h] + adh;
  x = fmaxf(x, SLOPE * x);
  return __expf(x);
}

template <bool ROOT>
__global__ __launch_bounds__(256)
void aggregate(const int* __restrict__ roots, const char* __restrict__ need,
               const int* __restrict__ cnt, const ushort* __restrict__ slots,
               const float* __restrict__ AS, const float* __restrict__ AD,
               const uint* __restrict__ XPu, const float* __restrict__ bvp,
               void* __restrict__ outp) {
  const int nid = blockIdx.x * 4 + (threadIdx.x >> 6);
  const int node = ROOT ? roots[nid] : nid;
  if (!ROOT && !need[node]) return;      // wave-uniform exit (~63% of nodes)
  const int l = threadIdx.x & 63;
  const int h = l & 3;
  const int deg = min(cnt[node * CSTR], CAP);
  const size_t base = (size_t)node << 6;
  const float adh = AD[((size_t)node << 2) + h];
  const int si = (int)slots[base + l];   // own slot entry (garbage if l>=deg)

  float ax = 0.f, ay = 0.f, den = 0.f;
  int e = 0;
  for (; e + 4 <= deg; e += 4) {
    const int s0 = __shfl(si, e),     s1 = __shfl(si, e + 1);
    const int s2 = __shfl(si, e + 2), s3 = __shfl(si, e + 3);
    const uint u0 = XPu[((size_t)s0 << 6) + l];
    const uint u1 = XPu[((size_t)s1 << 6) + l];
    const uint u2 = XPu[((size_t)s2 << 6) + l];
    const uint u3 = XPu[((size_t)s3 << 6) + l];
    const float w0 = wcalc(AS, s0, h, adh), w1 = wcalc(AS, s1, h, adh);
    const float w2 = wcalc(AS, s2, h, adh), w3 = wcalc(AS, s3, h, adh);
    ax += w0 * b2f_lo(u0) + w1 * b2f_lo(u1) + w2 * b2f_lo(u2) + w3 * b2f_lo(u3);
    ay += w0 * b2f_hi(u0) + w1 * b2f_hi(u1) + w2 * b2f_hi(u2) + w3 * b2f_hi(u3);
    den += (w0 + w1) + (w2 + w3);
  }
  for (; e < deg; ++e) {
    const int s = __shfl(si, e);
    const uint u = XPu[((size_t)s << 6) + l];
    const float w = wcalc(AS, s, h, adh);
    ax += w * b2f_lo(u);
    ay += w * b2f_hi(u);
    den += w;
  }

  const float inv = 1.f / (den + 1e-16f);
  const float2 bv = *(const float2*)(bvp + 2 * l);
  float rx = ax * inv + bv.x;
  float ry = ay * inv + bv.y;
  if (ROOT) {
    const int col0 = 32 * (l & 3) + (l >> 2);   // orig(2l); orig(2l+1)=col0+16
    float* o = (float*)outp + (size_t)nid * HC;
    o[col0] = rx;
    o[col0 + 16] = ry;
  } else {
    rx = fmaxf(rx, 0.f);
    ry = fmaxf(ry, 0.f);
    ((uint*)outp)[((size_t)node << 6) + l] = (uint)f2b(rx) | ((uint)f2b(ry) << 16);
  }
}

// ---------------------------------------------------------------------------
extern "C" void kernel_launch(void* const* d_in, const int* in_sizes, int n_in,
                              void* d_out, int out_size, void* d_ws, size_t ws_size,
                              hipStream_t stream) {
  const float* x    = (const float*)d_in[0];
  const int*   ei   = (const int*)d_in[1];
  const int*   root = (const int*)d_in[2];
  const float* W1   = (const float*)d_in[3];
  const float* as1  = (const float*)d_in[4];
  const float* ad1  = (const float*)d_in[5];
  const float* b1   = (const float*)d_in[6];
  const float* W2   = (const float*)d_in[7];
  const float* as2  = (const float*)d_in[8];
  const float* ad2  = (const float*)d_in[9];
  const float* b2   = (const float*)d_in[10];
  float* out = (float*)d_out;

  // workspace layout (16B-aligned segments), ~36 MB total
  ushort* W1t  = (ushort*)d_ws;                          // 64 KB
  ushort* W2t  = W1t + 4096 * 8;                         // 32 KB
  float*  vecs = (float*)(W2t + 2048 * 8);               // 3 KB
  ushort* XPp  = (ushort*)(vecs + 768);                  // [NN*HC] bf16
  ushort* Hbp  = XPp + (size_t)NN * HC;                  // [NN*HC] bf16
  float*  AS   = (float*)(Hbp + (size_t)NN * HC);        // [NN*4]
  float*  AD   = AS + (size_t)NN * 4;                    // [NN*4]
  int*    cnt  = (int*)(AD + (size_t)NN * 4);            // [NN*CSTR] strided
  ushort* slots = (ushort*)(cnt + (size_t)NN * CSTR);    // [NN*CAP] u16
  char*   need  = (char*)(slots + (size_t)NN * CAP);     // [NN]
  char*   rflag = need + NN;                             // [NN]

  const int n_root = out_size / HC;                      // 1024

  prep<<<224, 256, 0, stream>>>(W1, W2, as1, ad1, b1, as2, ad2, b2,
                                W1t, W2t, vecs, cnt, need, rflag);
  mark_roots<<<(n_root + 255) / 256, 256, 0, stream>>>(root, need, rflag,
                                                       n_root);
  pass1<<<EBLOCKS, 256, 0, stream>>>(ei, rflag, need);
  fillk<<<EBLOCKS, 256, 0, stream>>>(ei, need, cnt, slots);

  // ---- layer 1 ----
  gemm1<<<GB, 256, 0, stream>>>(x, W1t, vecs, vecs + 128, XPp, AS, AD);
  aggregate<false><<<NN / 4, 256, 0, stream>>>(nullptr, need, cnt, slots,
                                               AS, AD, (const uint*)XPp,
                                               vecs + 256, Hbp);

  // ---- layer 2 (aggregate only at the 1024 root nodes) ----
  gemm2<<<GB, 256, 0, stream>>>(Hbp, W2t, vecs + 384, vecs + 512,
                                XPp, AS, AD);
  aggregate<true><<<n_root / 4, 256, 0, stream>>>(root, need, cnt, slots,
                                                  AS, AD, (const uint*)XPp,
                                                  vecs + 640, out);
}